// Round 16
// baseline (183.743 us; speedup 1.0000x reference)
//
#include <hip/hip_runtime.h>

typedef __attribute__((ext_vector_type(8))) short bf16x8;
typedef __attribute__((ext_vector_type(4))) short s16x4;
typedef __attribute__((ext_vector_type(4))) float f32x4;
typedef __attribute__((ext_vector_type(16))) float f32x16;
typedef __attribute__((ext_vector_type(2))) unsigned u32x2;

#define MFMA16(a,b,c) __builtin_amdgcn_mfma_f32_16x16x32_bf16((a),(b),(c),0,0,0)
#define MFMA32(a,b,c) __builtin_amdgcn_mfma_f32_32x32x16_bf16((a),(b),(c),0,0,0)

static constexpr int Bsz = 4, T = 2048, E = 1024, NH = 16, HP = 64;
static constexpr int J3 = NH * 3 * HP;  // 3072

__device__ __forceinline__ short f2bf(float f) {
  union { float f; unsigned u; } v; v.f = f;
  unsigned r = (v.u + 0x7fffu + ((v.u >> 16) & 1u)) >> 16;
  return (short)r;
}

__device__ __forceinline__ unsigned cvtpk(float a, float b) {
  unsigned r;
  asm("v_cvt_pk_bf16_f32 %0, %1, %2" : "=v"(r) : "v"(a), "v"(b));
  return r;
}

typedef __attribute__((address_space(3))) unsigned int lds_u32;
typedef __attribute__((address_space(1))) const unsigned int glb_u32;
// async global->LDS, 16 B/lane; LDS dest = wave-uniform base + lane*16
__device__ __forceinline__ void gl16(const short* g, const short* l) {
  __builtin_amdgcn_global_load_lds((glb_u32*)g, (lds_u32*)l, 16, 0, 0);
}

// ---------------- fused converts (one dispatch, branch on block range) ----------------
__global__ void cvt_all(const float* __restrict__ x, s16x4* __restrict__ xb,
                        const float* __restrict__ wqkv, short* __restrict__ wqkvT,
                        const float* __restrict__ wo, short* __restrict__ woT) {
  __shared__ float tile[32][33];
  const int b = blockIdx.x;
  if (b < 8192) {
    int i = b * 256 + threadIdx.x;
    float4 v = ((const float4*)x)[i];
    s16x4 r;
    r[0] = f2bf(v.x); r[1] = f2bf(v.y); r[2] = f2bf(v.z); r[3] = f2bf(v.w);
    xb[i] = r;
  } else if (b < 11264) {
    const int bw = b - 8192;
    const int jb = (bw % 96) * 32, eb = (bw / 96) * 32;
    const int tx = threadIdx.x & 31, ty = threadIdx.x >> 5;   // 32x8
    for (int r = 0; r < 32; r += 8)
      tile[ty + r][tx] = wqkv[(size_t)(eb + ty + r) * J3 + jb + tx];
    __syncthreads();
    for (int r = 0; r < 32; r += 8)
      wqkvT[(size_t)(jb + ty + r) * E + eb + tx] = f2bf(tile[tx][ty + r]);
  } else {
    const int o = (b - 11264) * 256 + threadIdx.x;
    const int e = o >> 10, k = o & 1023;
    const int n = k >> 6, p = k & 63;
    woT[o] = f2bf(wo[(size_t)(p * 16 + n) * E + e]);
  }
}

// ---------------- GEMM1: qkv = x @ w_qkv, scatter to Q (scaled), K, V^T ----------------
// (R12 known-good loop) + T1 XCD-aware block remap: 1536 blocks = 8 XCD x
// (3 n-panels x 64 m-tiles); HW xcd = flat_bid % 8, so each XCD keeps 3 B-panels
// (768 KB) resident in its private L2 instead of re-fetching all 24.
__global__ __launch_bounds__(256) void gemm_qkv(
    const short* __restrict__ A,    // xb [8192][1024]
    const short* __restrict__ Bt,   // wqkvbT [3072][1024]
    const float* __restrict__ bias, // b_qkv flat [3072]
    short* __restrict__ Qb, short* __restrict__ Kb, short* __restrict__ Vt) {
  __shared__ short SH[17408];       // 34.8 KB: staging (32 KB) aliased w/ V-epi
  short* As = SH;                   // [128*64]
  short* Bs = SH + 8192;            // [128*64]
  const int f = blockIdx.y * 64 + blockIdx.x;
  const int xcd = f & 7, idx = f >> 3;            // 1536 = 8 * 192
  const int m0 = (idx & 63) * 128;                // m-tile (fastest within XCD)
  const int n0 = (xcd * 3 + (idx >> 6)) * 128;    // XCD's 3 n-panels
  const int tid = threadIdx.x;
  const int lane = tid & 63, w = tid >> 6;
  const int wm = (w >> 1) * 64, wn = (w & 1) * 64;
  const int l15 = lane & 15, lh = lane >> 4;
  const int l7 = l15 & 7;

  const int rA = lane >> 3;                       // row within chunk
  const int cS = 8 * ((lane & 7) ^ rA);           // pre-swizzled source col (shorts)
  const short* Ap = A + (size_t)(m0 + w * 32 + rA) * 1024 + cS;
  const short* Bp = Bt + (size_t)(n0 + w * 32 + rA) * 1024 + cS;
  const short* AsBase = As + w * 2048;
  const short* BsBase = Bs + w * 2048;

  f32x4 acc[4][4] = {};

  for (int k0 = 0; k0 < 1024; k0 += 64) {
    __syncthreads();                              // prev compute done
#pragma unroll
    for (int j = 0; j < 4; j++) {
      gl16(Ap + j * 8192 + k0, AsBase + j * 512);
      gl16(Bp + j * 8192 + k0, BsBase + j * 512);
    }
    __syncthreads();                              // vmcnt(0) drain before reads
    bf16x8 af[2][4], bfr[2][4];
#pragma unroll
    for (int kk = 0; kk < 2; kk++) {
#pragma unroll
      for (int m = 0; m < 4; m++)
        af[kk][m] = *(const bf16x8*)(As + (wm + m * 16 + l15) * 64 + 8 * ((kk * 4 + lh) ^ l7));
#pragma unroll
      for (int n = 0; n < 4; n++)
        bfr[kk][n] = *(const bf16x8*)(Bs + (wn + n * 16 + l15) * 64 + 8 * ((kk * 4 + lh) ^ l7));
    }
#pragma unroll
    for (int m = 0; m < 4; m++)
#pragma unroll
      for (int n = 0; n < 4; n++) {
        acc[m][n] = MFMA16(af[0][m], bfr[0][n], acc[m][n]);
        acc[m][n] = MFMA16(af[1][m], bfr[1][n], acc[m][n]);
      }
  }

  // ---- epilogue ----
  const int bb = m0 >> 11, m0t = m0 & 2047;
  const int g = w & 1;                 // wave's 64-col group (64-aligned => single ty)
  const int jg = n0 + g * 64;
  const int nhg = jg / 192;
  const int cg = jg - nhg * 192;
  const int tyg = cg >> 6;             // 0=Q 1=K 2=V

  __syncthreads();                     // all LDS reads done before SH reuse
  if (tyg == 2) {
    // write transposed [p][token] tile, b64-packed (pad-136 rows)
    short* Vl = SH + g * 8704;
#pragma unroll
    for (int nn = 0; nn < 4; nn++) {
      const int p = nn * 16 + l15;
      const float bv = bias[jg + p];
#pragma unroll
      for (int mm = 0; mm < 4; mm++) {
        const int tok0 = wm + mm * 16 + lh * 4;
        u32x2 pk;
        pk[0] = cvtpk(acc[mm][nn][0] + bv, acc[mm][nn][1] + bv);
        pk[1] = cvtpk(acc[mm][nn][2] + bv, acc[mm][nn][3] + bv);
        *(u32x2*)(Vl + p * 136 + tok0) = pk;
      }
    }
  } else {
    const float sc = (tyg == 0) ? 0.180336880f : 1.0f;  // Q: fold 1/sqrt(P)*log2e
    short* qkbase = ((tyg == 0) ? Qb : Kb) +
                    ((((size_t)(bb * 16 + nhg)) * 2048 + m0t) << 6);
#pragma unroll
    for (int nn = 0; nn < 4; nn++) {
      const int p = nn * 16 + l15;
      const float bv = bias[jg + p];
#pragma unroll
      for (int mm = 0; mm < 4; mm++) {
#pragma unroll
        for (int r = 0; r < 4; r++) {
          const int tok = wm + mm * 16 + lh * 4 + r;
          qkbase[(size_t)tok * 64 + p] = f2bf((acc[mm][nn][r] + bv) * sc);
        }
      }
    }
  }
  __syncthreads();
  // cooperative coalesced V stores: 64 p-rows x 256B contiguous tokens
#pragma unroll
  for (int g2 = 0; g2 < 2; g2++) {
    const int jg2 = n0 + g2 * 64;
    const int nh2 = jg2 / 192;
    const int c2 = jg2 - nh2 * 192;
    if ((c2 >> 6) == 2) {
      const short* Vl = SH + g2 * 8704;
      short* vout = Vt + ((size_t)(bb * 16 + nh2) << 6) * 2048 + m0t;
#pragma unroll
      for (int it = 0; it < 4; it++) {
        const int idx2 = it * 256 + tid;
        const int p = idx2 >> 4, ch = idx2 & 15;
        bf16x8 vv = *(const bf16x8*)(Vl + p * 136 + ch * 8);
        *(bf16x8*)(vout + (size_t)p * 2048 + ch * 8) = vv;
      }
    }
  }
}

// ---------------- flash attention: R12 verbatim (known-good 82us / 2.746e-4) ----------------
__global__ __launch_bounds__(512, 4) void attn(
    const short* __restrict__ Qb, const short* __restrict__ Kb,
    const short* __restrict__ Vt, short* __restrict__ Wt) {
  __shared__ short Kl[2][64 * 64];        // XOR-swizzled 128B rows
  __shared__ short Vl[2][64 * 64];
  const int bid = blockIdx.x;             // 512
  const int bn = bid & 63, qc = bid >> 6; // head -> fixed XCD
  const int tid = threadIdx.x, lane = tid & 63, w = tid >> 6;
  const int l31 = lane & 31, hi = lane >> 5, r7 = l31 & 7;
  const int q0 = qc * 256 + w * 32;

  const short* Qp = Qb + ((size_t)bn * 2048 + q0) * 64;
  const int rA = lane >> 3;
  const int cS = 8 * ((lane & 7) ^ rA);
  const short* Kg = Kb + (size_t)bn * 2048 * 64 + (w * 8 + rA) * 64 + cS;
  const short* Vg = Vt + (size_t)bn * 64 * 2048 + (size_t)(w * 8 + rA) * 2048 + cS;

  // Q fragments (B-operand, 32x32x16): B[k=p][col=q], k = kseg*16 + hi*8 + j
  bf16x8 qf[4];
#pragma unroll
  for (int kseg = 0; kseg < 4; kseg++)
    qf[kseg] = *(const bf16x8*)(Qp + l31 * 64 + kseg * 16 + hi * 8);

  float l = 0.f;
  f32x16 cin = {};                        // 0 for tile 0; splat(-m) after
  f32x16 o0 = {}, o1 = {};                // PV acc, p-groups 0/1

  gl16(Kg, &Kl[0][w * 512]);
  gl16(Vg, &Vl[0][w * 512]);
  __syncthreads();

  for (int t = 0; t < 32; t++) {
    const int cur = t & 1;
    if (t < 31) {
      gl16(Kg + (t + 1) * 4096, &Kl[cur ^ 1][w * 512]);
      gl16(Vg + (t + 1) * 64,   &Vl[cur ^ 1][w * 512]);
    }
    const short* Kc = &Kl[cur][0];
    const short* Vc = &Vl[cur][0];

    // QK^T: s0 = S[kv 0..31][q] - m, s1 = S[kv 32..63][q] - m (m via C-init)
    f32x16 s0, s1;
    {
      bf16x8 ka = *(const bf16x8*)(Kc + l31 * 64 + 8 * (hi ^ r7));
      s0 = MFMA32(ka, qf[0], cin);
    }
#pragma unroll
    for (int kseg = 1; kseg < 4; kseg++) {
      bf16x8 k0 = *(const bf16x8*)(Kc + l31 * 64 + 8 * ((kseg * 2 + hi) ^ r7));
      s0 = MFMA32(k0, qf[kseg], s0);
    }
    {
      bf16x8 kb = *(const bf16x8*)(Kc + (32 + l31) * 64 + 8 * (hi ^ ((32 + l31) & 7)));
      s1 = MFMA32(kb, qf[0], cin);
    }
#pragma unroll
    for (int kseg = 1; kseg < 4; kseg++) {
      bf16x8 k1 = *(const bf16x8*)(Kc + (32 + l31) * 64 + 8 * ((kseg * 2 + hi) ^ ((32 + l31) & 7)));
      s1 = MFMA32(k1, qf[kseg], s1);
    }

    if (t == 0) {          // one-time: m = tile-0 row max; bake -m into cin
      float pmax = fmaxf(s0[0], s0[1]);
#pragma unroll
      for (int r = 2; r < 16; r++) pmax = fmaxf(pmax, s0[r]);
#pragma unroll
      for (int r = 0; r < 16; r++) pmax = fmaxf(pmax, s1[r]);
      pmax = fmaxf(pmax, __shfl_xor(pmax, 32, 64));
#pragma unroll
      for (int r = 0; r < 16; r++) {
        s0[r] -= pmax; s1[r] -= pmax; cin[r] = -pmax;
      }
    }

    // P = exp2(s); row-sum
    float p0[16], p1[16], ps = 0.f;
#pragma unroll
    for (int r = 0; r < 16; r++) {
      p0[r] = __builtin_amdgcn_exp2f(s0[r]);
      p1[r] = __builtin_amdgcn_exp2f(s1[r]);
      ps += p0[r] + p1[r];
    }
    ps += __shfl_xor(ps, 32, 64);
    l += ps;

    // pack: w[kvg][rr*2+rp] holds P[kv = kvg*32 + 8*rr + 4*hi + 2*rp, +1][q]
    unsigned wk0[8], wk1[8];
#pragma unroll
    for (int rr = 0; rr < 4; rr++) {
#pragma unroll
      for (int rp = 0; rp < 2; rp++) {
        wk0[rr * 2 + rp] = cvtpk(p0[rr * 4 + 2 * rp], p0[rr * 4 + 2 * rp + 1]);
        wk1[rr * 2 + rp] = cvtpk(p1[rr * 4 + 2 * rp], p1[rr * 4 + 2 * rp + 1]);
      }
    }
    // B-frags pb[kseg]: P[kv = kseg*16 + hi*8 + j][q] via permlane32_swap
    union U8 { unsigned u[4]; bf16x8 v; };
    bf16x8 pb[4];
#pragma unroll
    for (int kseg = 0; kseg < 4; kseg++) {
      const int rrA = 2 * (kseg & 1);
      U8 u;
#pragma unroll
      for (int rp = 0; rp < 2; rp++) {
        unsigned a = (kseg < 2) ? wk0[rrA * 2 + rp] : wk1[rrA * 2 + rp];
        unsigned b = (kseg < 2) ? wk0[(rrA + 1) * 2 + rp] : wk1[(rrA + 1) * 2 + rp];
        asm("v_permlane32_swap_b32 %0, %1" : "+v"(a), "+v"(b));
        u.u[rp] = a;
        u.u[2 + rp] = b;
      }
      pb[kseg] = u.v;
    }

    // PV: o[pg] += mfma32(V^T rows p, P)
#pragma unroll
    for (int kseg = 0; kseg < 4; kseg++) {
      bf16x8 v0 = *(const bf16x8*)(Vc + l31 * 64 + 8 * ((kseg * 2 + hi) ^ r7));
      o0 = MFMA32(v0, pb[kseg], o0);
    }
#pragma unroll
    for (int kseg = 0; kseg < 4; kseg++) {
      bf16x8 v1 = *(const bf16x8*)(Vc + (32 + l31) * 64 + 8 * ((kseg * 2 + hi) ^ ((32 + l31) & 7)));
      o1 = MFMA32(v1, pb[kseg], o1);
    }
    __syncthreads();   // drains prefetch vmcnt + LDS reads before buffer swap
  }

  const float invl = 1.0f / l;
  const int bb = bn >> 4, n = bn & 15;
  short* wrow = Wt + (size_t)(bb * 2048 + q0 + l31) * 1024 + n * 64;
#pragma unroll
  for (int rr = 0; rr < 4; rr++) {
    s16x4 pk0, pk1;
#pragma unroll
    for (int j = 0; j < 4; j++) {
      pk0[j] = f2bf(o0[rr * 4 + j] * invl);
      pk1[j] = f2bf(o1[rr * 4 + j] * invl);
    }
    *(s16x4*)(wrow + 8 * rr + 4 * hi) = pk0;
    *(s16x4*)(wrow + 32 + 8 * rr + 4 * hi) = pk1;
  }
}

// ---------------- GEMM2: out = weighted @ w_o + b_o (f32 out) ----------------
// (R12 known-good loop) + T1 XCD remap: 512 = 8 XCD x 64 m; n-panel == XCD.
__global__ __launch_bounds__(256) void gemm_o(
    const short* __restrict__ A,   // Wt [8192][1024]
    const short* __restrict__ Bt,  // wobT [1024][1024]
    const float* __restrict__ bo,  // [1024]
    float* __restrict__ out) {     // [8192][1024]
  __shared__ short As[128 * 64];
  __shared__ short Bs[128 * 64];
  const int f = blockIdx.y * 64 + blockIdx.x;
  const int m0 = (f >> 3) * 128;
  const int n0 = (f & 7) * 128;
  const int tid = threadIdx.x;
  const int lane = tid & 63, w = tid >> 6;
  const int wm = (w >> 1) * 64, wn = (w & 1) * 64;
  const int l15 = lane & 15, lh = lane >> 4;
  const int l7 = l15 & 7;

  const int rA = lane >> 3;
  const int cS = 8 * ((lane & 7) ^ rA);
  const short* Ap = A + (size_t)(m0 + w * 32 + rA) * 1024 + cS;
  const short* Bp = Bt + (size_t)(n0 + w * 32 + rA) * 1024 + cS;
  const short* AsBase = As + w * 2048;
  const short* BsBase = Bs + w * 2048;

  f32x4 acc[4][4] = {};

  for (int k0 = 0; k0 < 1024; k0 += 64) {
    __syncthreads();
#pragma unroll
    for (int j = 0; j < 4; j++) {
      gl16(Ap + j * 8192 + k0, AsBase + j * 512);
      gl16(Bp + j * 8192 + k0, BsBase + j * 512);
    }
    __syncthreads();
    bf16x8 af[2][4], bfr[2][4];
#pragma unroll
    for (int kk = 0; kk < 2; kk++) {
#pragma unroll
      for (int m = 0; m < 4; m++)
        af[kk][m] = *(const bf16x8*)(As + (wm + m * 16 + l15) * 64 + 8 * ((kk * 4 + lh) ^ l7));
#pragma unroll
      for (int n = 0; n < 4; n++)
        bfr[kk][n] = *(const bf16x8*)(Bs + (wn + n * 16 + l15) * 64 + 8 * ((kk * 4 + lh) ^ l7));
    }
#pragma unroll
    for (int m = 0; m < 4; m++)
#pragma unroll
      for (int n = 0; n < 4; n++) {
        acc[m][n] = MFMA16(af[0][m], bfr[0][n], acc[m][n]);
        acc[m][n] = MFMA16(af[1][m], bfr[1][n], acc[m][n]);
      }
  }

#pragma unroll
  for (int nn = 0; nn < 4; nn++) {
    int e = n0 + wn + nn * 16 + l15;
    float bv = bo[e];
#pragma unroll
    for (int mm = 0; mm < 4; mm++) {
#pragma unroll
      for (int r = 0; r < 4; r++) {
        int i = m0 + wm + mm * 16 + lh * 4 + r;
        out[(size_t)i * 1024 + e] = acc[mm][nn][r] + bv;
      }
    }
  }
}

extern "C" void kernel_launch(void* const* d_in, const int* in_sizes, int n_in,
                              void* d_out, int out_size, void* d_ws, size_t ws_size,
                              hipStream_t stream) {
  (void)in_sizes; (void)n_in; (void)out_size; (void)ws_size;
  const float* x     = (const float*)d_in[0];
  const float* w_qkv = (const float*)d_in[1];
  const float* b_qkv = (const float*)d_in[2];
  const float* w_o   = (const float*)d_in[3];
  const float* b_o   = (const float*)d_in[4];
  float* out = (float*)d_out;
  char* ws = (char*)d_ws;

  short* xb     = (short*)(ws);               // 16.8 MB  [8192][1024]
  short* wqkvbT = (short*)(ws + 16777216);    //  6.3 MB  [3072][1024]
  short* wobT   = (short*)(ws + 23068672);    //  2.1 MB  [1024][1024]
  short* Qb     = (short*)(ws + 25165824);    // 16.8 MB  [64][2048][64]
  short* Kb     = (short*)(ws + 41943040);    // 16.8 MB  [64][2048][64]
  short* Vt     = (short*)(ws + 58720256);    // 16.8 MB  [64][64][2048]
  short* Wt     = (short*)(ws + 75497472);    // 16.8 MB  [8192][1024]

  hipLaunchKernelGGL(cvt_all,  dim3(15360),   dim3(256), 0, stream,
                     x, (s16x4*)xb, w_qkv, wqkvbT, w_o, wobT);
  hipLaunchKernelGGL(gemm_qkv, dim3(64, 24),  dim3(256), 0, stream, xb, wqkvbT, b_qkv, Qb, Kb, Vt);
  hipLaunchKernelGGL(attn,     dim3(512),     dim3(512), 0, stream, Qb, Kb, Vt, Wt);
  hipLaunchKernelGGL(gemm_o,   dim3(64, 8),   dim3(256), 0, stream, Wt, wobT, b_o, out);
}

// Round 17
// 169.219 us; speedup vs baseline: 1.0858x; 1.0858x over previous
//
#include <hip/hip_runtime.h>

typedef __attribute__((ext_vector_type(8))) short bf16x8;
typedef __attribute__((ext_vector_type(4))) short s16x4;
typedef __attribute__((ext_vector_type(4))) float f32x4;
typedef __attribute__((ext_vector_type(16))) float f32x16;
typedef __attribute__((ext_vector_type(2))) unsigned u32x2;

#define MFMA16(a,b,c) __builtin_amdgcn_mfma_f32_16x16x32_bf16((a),(b),(c),0,0,0)
#define MFMA32(a,b,c) __builtin_amdgcn_mfma_f32_32x32x16_bf16((a),(b),(c),0,0,0)

static constexpr int Bsz = 4, T = 2048, E = 1024, NH = 16, HP = 64;
static constexpr int J3 = NH * 3 * HP;  // 3072

__device__ __forceinline__ short f2bf(float f) {
  union { float f; unsigned u; } v; v.f = f;
  unsigned r = (v.u + 0x7fffu + ((v.u >> 16) & 1u)) >> 16;
  return (short)r;
}

__device__ __forceinline__ unsigned cvtpk(float a, float b) {
  unsigned r;
  asm("v_cvt_pk_bf16_f32 %0, %1, %2" : "=v"(r) : "v"(a), "v"(b));
  return r;
}

typedef __attribute__((address_space(3))) unsigned int lds_u32;
typedef __attribute__((address_space(1))) const unsigned int glb_u32;
// async global->LDS, 16 B/lane; LDS dest = wave-uniform base + lane*16
__device__ __forceinline__ void gl16(const short* g, const short* l) {
  __builtin_amdgcn_global_load_lds((glb_u32*)g, (lds_u32*)l, 16, 0, 0);
}

// ---------------- fused converts (one dispatch, branch on block range) ----------------
__global__ void cvt_all(const float* __restrict__ x, s16x4* __restrict__ xb,
                        const float* __restrict__ wqkv, short* __restrict__ wqkvT,
                        const float* __restrict__ wo, short* __restrict__ woT) {
  __shared__ float tile[32][33];
  const int b = blockIdx.x;
  if (b < 8192) {
    int i = b * 256 + threadIdx.x;
    float4 v = ((const float4*)x)[i];
    s16x4 r;
    r[0] = f2bf(v.x); r[1] = f2bf(v.y); r[2] = f2bf(v.z); r[3] = f2bf(v.w);
    xb[i] = r;
  } else if (b < 11264) {
    const int bw = b - 8192;
    const int jb = (bw % 96) * 32, eb = (bw / 96) * 32;
    const int tx = threadIdx.x & 31, ty = threadIdx.x >> 5;   // 32x8
    for (int r = 0; r < 32; r += 8)
      tile[ty + r][tx] = wqkv[(size_t)(eb + ty + r) * J3 + jb + tx];
    __syncthreads();
    for (int r = 0; r < 32; r += 8)
      wqkvT[(size_t)(jb + ty + r) * E + eb + tx] = f2bf(tile[tx][ty + r]);
  } else {
    const int o = (b - 11264) * 256 + threadIdx.x;
    const int e = o >> 10, k = o & 1023;
    const int n = k >> 6, p = k & 63;
    woT[o] = f2bf(wo[(size_t)(p * 16 + n) * E + e]);
  }
}

// ---------------- GEMM1: qkv = x @ w_qkv, scatter to Q (scaled), K, V^T ----------------
// (R12 known-good form; natural m-fastest block order — T1 remap refuted in R16)
__global__ __launch_bounds__(256) void gemm_qkv(
    const short* __restrict__ A,    // xb [8192][1024]
    const short* __restrict__ Bt,   // wqkvbT [3072][1024]
    const float* __restrict__ bias, // b_qkv flat [3072]
    short* __restrict__ Qb, short* __restrict__ Kb, short* __restrict__ Vt) {
  __shared__ short SH[17408];       // 34.8 KB: staging (32 KB) aliased w/ V-epi
  short* As = SH;                   // [128*64]
  short* Bs = SH + 8192;            // [128*64]
  const int m0 = blockIdx.x * 128, n0 = blockIdx.y * 128;
  const int tid = threadIdx.x;
  const int lane = tid & 63, w = tid >> 6;
  const int wm = (w >> 1) * 64, wn = (w & 1) * 64;
  const int l15 = lane & 15, lh = lane >> 4;
  const int l7 = l15 & 7;

  const int rA = lane >> 3;                       // row within chunk
  const int cS = 8 * ((lane & 7) ^ rA);           // pre-swizzled source col (shorts)
  const short* Ap = A + (size_t)(m0 + w * 32 + rA) * 1024 + cS;
  const short* Bp = Bt + (size_t)(n0 + w * 32 + rA) * 1024 + cS;
  const short* AsBase = As + w * 2048;
  const short* BsBase = Bs + w * 2048;

  f32x4 acc[4][4] = {};

  for (int k0 = 0; k0 < 1024; k0 += 64) {
    __syncthreads();                              // prev compute done
#pragma unroll
    for (int j = 0; j < 4; j++) {
      gl16(Ap + j * 8192 + k0, AsBase + j * 512);
      gl16(Bp + j * 8192 + k0, BsBase + j * 512);
    }
    __syncthreads();                              // vmcnt(0) drain before reads
    bf16x8 af[2][4], bfr[2][4];
#pragma unroll
    for (int kk = 0; kk < 2; kk++) {
#pragma unroll
      for (int m = 0; m < 4; m++)
        af[kk][m] = *(const bf16x8*)(As + (wm + m * 16 + l15) * 64 + 8 * ((kk * 4 + lh) ^ l7));
#pragma unroll
      for (int n = 0; n < 4; n++)
        bfr[kk][n] = *(const bf16x8*)(Bs + (wn + n * 16 + l15) * 64 + 8 * ((kk * 4 + lh) ^ l7));
    }
#pragma unroll
    for (int m = 0; m < 4; m++)
#pragma unroll
      for (int n = 0; n < 4; n++) {
        acc[m][n] = MFMA16(af[0][m], bfr[0][n], acc[m][n]);
        acc[m][n] = MFMA16(af[1][m], bfr[1][n], acc[m][n]);
      }
  }

  // ---- epilogue ----
  const int bb = m0 >> 11, m0t = m0 & 2047;
  const int g = w & 1;                 // wave's 64-col group (64-aligned => single ty)
  const int jg = n0 + g * 64;
  const int nhg = jg / 192;
  const int cg = jg - nhg * 192;
  const int tyg = cg >> 6;             // 0=Q 1=K 2=V

  __syncthreads();                     // all LDS reads done before SH reuse
  if (tyg == 2) {
    // write transposed [p][token] tile, b64-packed (pad-136 rows)
    short* Vl = SH + g * 8704;
#pragma unroll
    for (int nn = 0; nn < 4; nn++) {
      const int p = nn * 16 + l15;
      const float bv = bias[jg + p];
#pragma unroll
      for (int mm = 0; mm < 4; mm++) {
        const int tok0 = wm + mm * 16 + lh * 4;
        u32x2 pk;
        pk[0] = cvtpk(acc[mm][nn][0] + bv, acc[mm][nn][1] + bv);
        pk[1] = cvtpk(acc[mm][nn][2] + bv, acc[mm][nn][3] + bv);
        *(u32x2*)(Vl + p * 136 + tok0) = pk;
      }
    }
  } else {
    const float sc = (tyg == 0) ? 0.180336880f : 1.0f;  // Q: fold 1/sqrt(P)*log2e
    short* qkbase = ((tyg == 0) ? Qb : Kb) +
                    ((((size_t)(bb * 16 + nhg)) * 2048 + m0t) << 6);
#pragma unroll
    for (int nn = 0; nn < 4; nn++) {
      const int p = nn * 16 + l15;
      const float bv = bias[jg + p];
#pragma unroll
      for (int mm = 0; mm < 4; mm++) {
#pragma unroll
        for (int r = 0; r < 4; r++) {
          const int tok = wm + mm * 16 + lh * 4 + r;
          qkbase[(size_t)tok * 64 + p] = f2bf((acc[mm][nn][r] + bv) * sc);
        }
      }
    }
  }
  __syncthreads();
  // cooperative coalesced V stores: 64 p-rows x 256B contiguous tokens
#pragma unroll
  for (int g2 = 0; g2 < 2; g2++) {
    const int jg2 = n0 + g2 * 64;
    const int nh2 = jg2 / 192;
    const int c2 = jg2 - nh2 * 192;
    if ((c2 >> 6) == 2) {
      const short* Vl = SH + g2 * 8704;
      short* vout = Vt + ((size_t)(bb * 16 + nh2) << 6) * 2048 + m0t;
#pragma unroll
      for (int it = 0; it < 4; it++) {
        const int idx = it * 256 + tid;
        const int p = idx >> 4, ch = idx & 15;
        bf16x8 vv = *(const bf16x8*)(Vl + p * 136 + ch * 8);
        *(bf16x8*)(vout + (size_t)p * 2048 + ch * 8) = vv;
      }
    }
  }
}

// ---------------- flash attention: 32x32 MFMA, in-register P, tile-0-max softmax ----------------
// (R12 verbatim — known-good 82us / absmax 2.746e-4)
__global__ __launch_bounds__(512, 4) void attn(
    const short* __restrict__ Qb, const short* __restrict__ Kb,
    const short* __restrict__ Vt, short* __restrict__ Wt) {
  __shared__ short Kl[2][64 * 64];        // XOR-swizzled 128B rows
  __shared__ short Vl[2][64 * 64];
  const int bid = blockIdx.x;             // 512
  const int bn = bid & 63, qc = bid >> 6; // head -> fixed XCD
  const int tid = threadIdx.x, lane = tid & 63, w = tid >> 6;
  const int l31 = lane & 31, hi = lane >> 5, r7 = l31 & 7;
  const int q0 = qc * 256 + w * 32;

  const short* Qp = Qb + ((size_t)bn * 2048 + q0) * 64;
  const int rA = lane >> 3;
  const int cS = 8 * ((lane & 7) ^ rA);
  const short* Kg = Kb + (size_t)bn * 2048 * 64 + (w * 8 + rA) * 64 + cS;
  const short* Vg = Vt + (size_t)bn * 64 * 2048 + (size_t)(w * 8 + rA) * 2048 + cS;

  // Q fragments (B-operand, 32x32x16): B[k=p][col=q], k = kseg*16 + hi*8 + j
  bf16x8 qf[4];
#pragma unroll
  for (int kseg = 0; kseg < 4; kseg++)
    qf[kseg] = *(const bf16x8*)(Qp + l31 * 64 + kseg * 16 + hi * 8);

  float l = 0.f;
  f32x16 cin = {};                        // 0 for tile 0; splat(-m) after
  f32x16 o0 = {}, o1 = {};                // PV acc, p-groups 0/1

  gl16(Kg, &Kl[0][w * 512]);
  gl16(Vg, &Vl[0][w * 512]);
  __syncthreads();

  for (int t = 0; t < 32; t++) {
    const int cur = t & 1;
    if (t < 31) {
      gl16(Kg + (t + 1) * 4096, &Kl[cur ^ 1][w * 512]);
      gl16(Vg + (t + 1) * 64,   &Vl[cur ^ 1][w * 512]);
    }
    const short* Kc = &Kl[cur][0];
    const short* Vc = &Vl[cur][0];

    // QK^T: s0 = S[kv 0..31][q] - m, s1 = S[kv 32..63][q] - m (m via C-init)
    f32x16 s0, s1;
    {
      bf16x8 ka = *(const bf16x8*)(Kc + l31 * 64 + 8 * (hi ^ r7));
      s0 = MFMA32(ka, qf[0], cin);
    }
#pragma unroll
    for (int kseg = 1; kseg < 4; kseg++) {
      bf16x8 k0 = *(const bf16x8*)(Kc + l31 * 64 + 8 * ((kseg * 2 + hi) ^ r7));
      s0 = MFMA32(k0, qf[kseg], s0);
    }
    {
      bf16x8 kb = *(const bf16x8*)(Kc + (32 + l31) * 64 + 8 * (hi ^ ((32 + l31) & 7)));
      s1 = MFMA32(kb, qf[0], cin);
    }
#pragma unroll
    for (int kseg = 1; kseg < 4; kseg++) {
      bf16x8 k1 = *(const bf16x8*)(Kc + (32 + l31) * 64 + 8 * ((kseg * 2 + hi) ^ ((32 + l31) & 7)));
      s1 = MFMA32(k1, qf[kseg], s1);
    }

    if (t == 0) {          // one-time: m = tile-0 row max; bake -m into cin
      float pmax = fmaxf(s0[0], s0[1]);
#pragma unroll
      for (int r = 2; r < 16; r++) pmax = fmaxf(pmax, s0[r]);
#pragma unroll
      for (int r = 0; r < 16; r++) pmax = fmaxf(pmax, s1[r]);
      pmax = fmaxf(pmax, __shfl_xor(pmax, 32, 64));
#pragma unroll
      for (int r = 0; r < 16; r++) {
        s0[r] -= pmax; s1[r] -= pmax; cin[r] = -pmax;
      }
    }

    // P = exp2(s); row-sum
    float p0[16], p1[16], ps = 0.f;
#pragma unroll
    for (int r = 0; r < 16; r++) {
      p0[r] = __builtin_amdgcn_exp2f(s0[r]);
      p1[r] = __builtin_amdgcn_exp2f(s1[r]);
      ps += p0[r] + p1[r];
    }
    ps += __shfl_xor(ps, 32, 64);
    l += ps;

    // pack: w[kvg][rr*2+rp] holds P[kv = kvg*32 + 8*rr + 4*hi + 2*rp, +1][q]
    unsigned wk0[8], wk1[8];
#pragma unroll
    for (int rr = 0; rr < 4; rr++) {
#pragma unroll
      for (int rp = 0; rp < 2; rp++) {
        wk0[rr * 2 + rp] = cvtpk(p0[rr * 4 + 2 * rp], p0[rr * 4 + 2 * rp + 1]);
        wk1[rr * 2 + rp] = cvtpk(p1[rr * 4 + 2 * rp], p1[rr * 4 + 2 * rp + 1]);
      }
    }
    // B-frags pb[kseg]: P[kv = kseg*16 + hi*8 + j][q] via permlane32_swap
    union U8 { unsigned u[4]; bf16x8 v; };
    bf16x8 pb[4];
#pragma unroll
    for (int kseg = 0; kseg < 4; kseg++) {
      const int rrA = 2 * (kseg & 1);
      U8 u;
#pragma unroll
      for (int rp = 0; rp < 2; rp++) {
        unsigned a = (kseg < 2) ? wk0[rrA * 2 + rp] : wk1[rrA * 2 + rp];
        unsigned b = (kseg < 2) ? wk0[(rrA + 1) * 2 + rp] : wk1[(rrA + 1) * 2 + rp];
        asm("v_permlane32_swap_b32 %0, %1" : "+v"(a), "+v"(b));
        u.u[rp] = a;
        u.u[2 + rp] = b;
      }
      pb[kseg] = u.v;
    }

    // PV: o[pg] += mfma32(V^T rows p, P)
#pragma unroll
    for (int kseg = 0; kseg < 4; kseg++) {
      bf16x8 v0 = *(const bf16x8*)(Vc + l31 * 64 + 8 * ((kseg * 2 + hi) ^ r7));
      o0 = MFMA32(v0, pb[kseg], o0);
    }
#pragma unroll
    for (int kseg = 0; kseg < 4; kseg++) {
      bf16x8 v1 = *(const bf16x8*)(Vc + (32 + l31) * 64 + 8 * ((kseg * 2 + hi) ^ ((32 + l31) & 7)));
      o1 = MFMA32(v1, pb[kseg], o1);
    }
    __syncthreads();   // drains prefetch vmcnt + LDS reads before buffer swap
  }

  const float invl = 1.0f / l;
  const int bb = bn >> 4, n = bn & 15;
  short* wrow = Wt + (size_t)(bb * 2048 + q0 + l31) * 1024 + n * 64;
#pragma unroll
  for (int rr = 0; rr < 4; rr++) {
    s16x4 pk0, pk1;
#pragma unroll
    for (int j = 0; j < 4; j++) {
      pk0[j] = f2bf(o0[rr * 4 + j] * invl);
      pk1[j] = f2bf(o1[rr * 4 + j] * invl);
    }
    *(s16x4*)(wrow + 8 * rr + 4 * hi) = pk0;
    *(s16x4*)(wrow + 32 + 8 * rr + 4 * hi) = pk1;
  }
}

// ---------------- GEMM2: out = weighted @ w_o + b_o (f32 out) ----------------
// (R12 known-good form; natural block order)
__global__ __launch_bounds__(256) void gemm_o(
    const short* __restrict__ A,   // Wt [8192][1024]
    const short* __restrict__ Bt,  // wobT [1024][1024]
    const float* __restrict__ bo,  // [1024]
    float* __restrict__ out) {     // [8192][1024]
  __shared__ short As[128 * 64];
  __shared__ short Bs[128 * 64];
  const int m0 = blockIdx.x * 128, n0 = blockIdx.y * 128;
  const int tid = threadIdx.x;
  const int lane = tid & 63, w = tid >> 6;
  const int wm = (w >> 1) * 64, wn = (w & 1) * 64;
  const int l15 = lane & 15, lh = lane >> 4;
  const int l7 = l15 & 7;

  const int rA = lane >> 3;
  const int cS = 8 * ((lane & 7) ^ rA);
  const short* Ap = A + (size_t)(m0 + w * 32 + rA) * 1024 + cS;
  const short* Bp = Bt + (size_t)(n0 + w * 32 + rA) * 1024 + cS;
  const short* AsBase = As + w * 2048;
  const short* BsBase = Bs + w * 2048;

  f32x4 acc[4][4] = {};

  for (int k0 = 0; k0 < 1024; k0 += 64) {
    __syncthreads();
#pragma unroll
    for (int j = 0; j < 4; j++) {
      gl16(Ap + j * 8192 + k0, AsBase + j * 512);
      gl16(Bp + j * 8192 + k0, BsBase + j * 512);
    }
    __syncthreads();
    bf16x8 af[2][4], bfr[2][4];
#pragma unroll
    for (int kk = 0; kk < 2; kk++) {
#pragma unroll
      for (int m = 0; m < 4; m++)
        af[kk][m] = *(const bf16x8*)(As + (wm + m * 16 + l15) * 64 + 8 * ((kk * 4 + lh) ^ l7));
#pragma unroll
      for (int n = 0; n < 4; n++)
        bfr[kk][n] = *(const bf16x8*)(Bs + (wn + n * 16 + l15) * 64 + 8 * ((kk * 4 + lh) ^ l7));
    }
#pragma unroll
    for (int m = 0; m < 4; m++)
#pragma unroll
      for (int n = 0; n < 4; n++) {
        acc[m][n] = MFMA16(af[0][m], bfr[0][n], acc[m][n]);
        acc[m][n] = MFMA16(af[1][m], bfr[1][n], acc[m][n]);
      }
  }

#pragma unroll
  for (int nn = 0; nn < 4; nn++) {
    int e = n0 + wn + nn * 16 + l15;
    float bv = bo[e];
#pragma unroll
    for (int mm = 0; mm < 4; mm++) {
#pragma unroll
      for (int r = 0; r < 4; r++) {
        int i = m0 + wm + mm * 16 + lh * 4 + r;
        out[(size_t)i * 1024 + e] = acc[mm][nn][r] + bv;
      }
    }
  }
}

extern "C" void kernel_launch(void* const* d_in, const int* in_sizes, int n_in,
                              void* d_out, int out_size, void* d_ws, size_t ws_size,
                              hipStream_t stream) {
  (void)in_sizes; (void)n_in; (void)out_size; (void)ws_size;
  const float* x     = (const float*)d_in[0];
  const float* w_qkv = (const float*)d_in[1];
  const float* b_qkv = (const float*)d_in[2];
  const float* w_o   = (const float*)d_in[3];
  const float* b_o   = (const float*)d_in[4];
  float* out = (float*)d_out;
  char* ws = (char*)d_ws;

  short* xb     = (short*)(ws);               // 16.8 MB  [8192][1024]
  short* wqkvbT = (short*)(ws + 16777216);    //  6.3 MB  [3072][1024]
  short* wobT   = (short*)(ws + 23068672);    //  2.1 MB  [1024][1024]
  short* Qb     = (short*)(ws + 25165824);    // 16.8 MB  [64][2048][64]
  short* Kb     = (short*)(ws + 41943040);    // 16.8 MB  [64][2048][64]
  short* Vt     = (short*)(ws + 58720256);    // 16.8 MB  [64][64][2048]
  short* Wt     = (short*)(ws + 75497472);    // 16.8 MB  [8192][1024]

  hipLaunchKernelGGL(cvt_all,  dim3(15360),   dim3(256), 0, stream,
                     x, (s16x4*)xb, w_qkv, wqkvbT, w_o, wobT);
  hipLaunchKernelGGL(gemm_qkv, dim3(64, 24),  dim3(256), 0, stream, xb, wqkvbT, b_qkv, Qb, Kb, Vt);
  hipLaunchKernelGGL(attn,     dim3(512),     dim3(512), 0, stream, Qb, Kb, Vt, Wt);
  hipLaunchKernelGGL(gemm_o,   dim3(64, 8),   dim3(256), 0, stream, Wt, wobT, b_o, out);
}